// Round 3
// baseline (922.618 us; speedup 1.0000x reference)
//
#include <hip/hip_runtime.h>
#include <hip/hip_bf16.h>
#include <stdint.h>

#define N_ROWS 16384
#define M_ROWS 4096
#define DDIM   512
#define BK     32
#define NKT    (DDIM / BK)   // 16 K-tiles

using frag_ab = __attribute__((ext_vector_type(8))) short;  // 8 bf16 (4 VGPRs)
using frag_cd = __attribute__((ext_vector_type(4))) float;  // 4 fp32 acc

__device__ __forceinline__ unsigned short f2bf(float f) {
  unsigned int u = __float_as_uint(f);
  u += 0x7fffu + ((u >> 16) & 1u);   // round-to-nearest-even
  return (unsigned short)(u >> 16);
}

// FULLY FUSED kernel: out = ||x||^2 + ||c||^2 - 2 * (x . c^T), straight from
// the fp32 inputs. No separate convert pass, no workspace at all.
//
// Rationale (round-3): three structurally different GEMM schedules all
// measured 357+-2 us; our dispatches never exceed the ~170 us poison
// fills, and the fills come in 1-GiB pairs (~340 us) => the timed region
// is dominated by harness fill traffic, our kernels are the tail. The
// remaining lever is the tail: fuse conversion+norms into the GEMM,
// eliminating the convert dispatch and the entire 0.5 GB workspace
// round-trip against a freshly poisoned buffer.
//
// Structure: 256x256 tile, 8 waves (2x4), 128x64 out/wave. Per K-tile
// (BK=32): each thread loads 16 fp32 of A-rows + 16 fp32 of B-rows
// (64 B contiguous each), accumulates row-norm partials in fp32,
// converts to bf16 (RNE), ds_writes 2x16 B swizzled chunks per operand.
// Double-buffered LDS (2 slots x 16 KB x 2 operands = 64 KB + 2 KB norms),
// one barrier per K-tile, loads for kt+1 issued before kt's MFMA (T14:
// HBM latency hides under MFMA; compiler places the vmcnt before first
// use at cvt). LDS XOR-swizzle byte^=(byte>>3)&48 on BOTH write and read
// sides (both-sides rule; no global_load_lds anywhere, so swizzled
// ds_write is legal). Row norms: per-thread partials over its 16-col
// half, shfl_xor(1) pair-reduce, staged via 256-float LDS arrays.
//
// Cache shaping: xcd-banded n-fast mapping with 4-tile bands so the fp32
// working set (4x256 A-rows = 2 MB + 256 B-rows = 0.5 MB) fits a 4 MiB
// XCD L2. Unique HBM reads ~40 MB; writes 268 MB (the floor).
__global__ __launch_bounds__(512, 2) void rbf_fused_kernel(
    const float* __restrict__ in,    // [N, D] fp32
    const float* __restrict__ cen,   // [M, D] fp32
    float* __restrict__ out) {
  __shared__ __attribute__((aligned(16))) unsigned short A_lds[2][256 * BK];
  __shared__ __attribute__((aligned(16))) unsigned short B_lds[2][256 * BK];
  __shared__ float An[256];
  __shared__ float Bn[256];

  const int tid    = threadIdx.x;
  const int wid    = tid >> 6;
  const int lane   = tid & 63;
  const int lane15 = lane & 15;
  const int quad   = lane >> 4;
  const int wm     = wid >> 2;  // 0..1 : 128-row (n) half
  const int wn     = wid & 3;   // 0..3 : 64-col (m) quarter

  // XCD-banded bijective mapping over 16 m-tiles x 64 n-tiles.
  // Band of 4 n-tiles per XCD epoch -> 2.5 MB fp32 working set < 4 MiB L2.
  const int orig = blockIdx.x;        // 0..1023
  const int xcd  = orig & 7;
  const int s    = orig >> 3;         // 0..127
  const int band = s >> 6;            // 0..1
  const int r    = s & 63;
  const int m0   = (r >> 2) * 256;                    // m-tile, slow
  const int n0   = (band * 32 + xcd * 4 + (r & 3)) * 256;  // n-tile, fast

  // Staging assignment: thread -> (row = tid>>1, 16-float half = tid&1).
  const int srow  = tid >> 1;
  const int shalf = tid & 1;
  const float* gA = in  + (size_t)(n0 + srow) * DDIM + shalf * 16;
  const float* gB = cen + (size_t)(m0 + srow) * DDIM + shalf * 16;

  // Swizzled LDS write offsets (bytes, slot-relative): logical row-major
  // [256][32] bf16 (64 B rows), 16 B chunks XOR-swizzled.
  const int Lw  = srow * 64 + shalf * 32;
  const int sw0 = Lw ^ ((Lw >> 3) & 48);
  const int Lw1 = Lw + 16;
  const int sw1 = Lw1 ^ ((Lw1 >> 3) & 48);

  // Fragment read offsets (slot-relative, swizzled) - same layout law.
  int offA[8], offB[4];
#pragma unroll
  for (int i = 0; i < 8; ++i) {
    const int row = wm * 128 + i * 16 + lane15;
    const int L   = row * 64 + quad * 16;
    offA[i] = L ^ ((L >> 3) & 48);
  }
#pragma unroll
  for (int j = 0; j < 4; ++j) {
    const int row = wn * 64 + j * 16 + lane15;
    const int L   = row * 64 + quad * 16;
    offB[j] = L ^ ((L >> 3) & 48);
  }

  frag_cd acc[8][4];
#pragma unroll
  for (int i = 0; i < 8; ++i)
#pragma unroll
    for (int j = 0; j < 4; ++j)
      acc[i][j] = (frag_cd){0.f, 0.f, 0.f, 0.f};

  float4 ra[4], rb[4];
  float pnA = 0.f, pnB = 0.f;

  auto load_regs = [&](int kt) {
#pragma unroll
    for (int c = 0; c < 4; ++c) {
      ra[c] = *(const float4*)(gA + kt * BK + c * 4);
      rb[c] = *(const float4*)(gB + kt * BK + c * 4);
    }
  };

  auto cvt_write = [&](int slot) {
    unsigned int ua[8], ub[8];
#pragma unroll
    for (int c = 0; c < 4; ++c) {
      pnA += ra[c].x * ra[c].x + ra[c].y * ra[c].y +
             ra[c].z * ra[c].z + ra[c].w * ra[c].w;
      pnB += rb[c].x * rb[c].x + rb[c].y * rb[c].y +
             rb[c].z * rb[c].z + rb[c].w * rb[c].w;
      ua[c * 2]     = (unsigned)f2bf(ra[c].x) | ((unsigned)f2bf(ra[c].y) << 16);
      ua[c * 2 + 1] = (unsigned)f2bf(ra[c].z) | ((unsigned)f2bf(ra[c].w) << 16);
      ub[c * 2]     = (unsigned)f2bf(rb[c].x) | ((unsigned)f2bf(rb[c].y) << 16);
      ub[c * 2 + 1] = (unsigned)f2bf(rb[c].z) | ((unsigned)f2bf(rb[c].w) << 16);
    }
    char* Ab = (char*)&A_lds[slot][0];
    char* Bb = (char*)&B_lds[slot][0];
    *(uint4*)(Ab + sw0) = (uint4){ua[0], ua[1], ua[2], ua[3]};
    *(uint4*)(Ab + sw1) = (uint4){ua[4], ua[5], ua[6], ua[7]};
    *(uint4*)(Bb + sw0) = (uint4){ub[0], ub[1], ub[2], ub[3]};
    *(uint4*)(Bb + sw1) = (uint4){ub[4], ub[5], ub[6], ub[7]};
  };

  // Prologue: stage K-tile 0.
  load_regs(0);
  cvt_write(0);
  __syncthreads();

#pragma unroll
  for (int kt = 0; kt < NKT; ++kt) {
    // Issue next tile's global loads early; first use is in cvt_write
    // after the MFMAs, so the compiler's vmcnt lands there (T14).
    if (kt + 1 < NKT) load_regs(kt + 1);

    const char* Ab = (const char*)&A_lds[kt & 1][0];
    const char* Bb = (const char*)&B_lds[kt & 1][0];
    frag_ab a[8], b[4];
#pragma unroll
    for (int j = 0; j < 4; ++j) b[j] = *(const frag_ab*)(Bb + offB[j]);
#pragma unroll
    for (int i = 0; i < 8; ++i) a[i] = *(const frag_ab*)(Ab + offA[i]);

    __builtin_amdgcn_s_setprio(1);
#pragma unroll
    for (int i = 0; i < 8; ++i)
#pragma unroll
      for (int j = 0; j < 4; ++j)
        acc[i][j] = __builtin_amdgcn_mfma_f32_16x16x32_bf16(
            a[i], b[j], acc[i][j], 0, 0, 0);
    __builtin_amdgcn_s_setprio(0);

    // Write kt+1 into the other slot. Its previous readers (iteration
    // kt-1) are behind the barrier ending kt-1; this iteration's readers
    // of slot kt&1 are untouched. One barrier per K-tile.
    if (kt + 1 < NKT) cvt_write((kt + 1) & 1);
    __syncthreads();
  }

  // Row norms: pair-reduce the two 16-col halves, stage via LDS.
  pnA += __shfl_xor(pnA, 1, 64);
  pnB += __shfl_xor(pnB, 1, 64);
  if (shalf == 0) { An[srow] = pnA; Bn[srow] = pnB; }
  __syncthreads();

  // Epilogue: out[r][c] = ||x_r||^2 + ||c_c||^2 - 2*dot.
  // C/D layout: col = lane&15, row = quad*4 + reg (m89-verified).
  float cs[4];
#pragma unroll
  for (int j = 0; j < 4; ++j) cs[j] = Bn[wn * 64 + j * 16 + lane15];

#pragma unroll
  for (int i = 0; i < 8; ++i) {
#pragma unroll
    for (int reg = 0; reg < 4; ++reg) {
      const int rl = wm * 128 + i * 16 + quad * 4 + reg;
      const float xv = An[rl];
      float* orow = out + (size_t)(n0 + rl) * M_ROWS + m0 + wn * 64 + lane15;
#pragma unroll
      for (int j = 0; j < 4; ++j) {
        orow[j * 16] = xv + cs[j] - 2.0f * acc[i][j][reg];
      }
    }
  }
}

extern "C" void kernel_launch(void* const* d_in, const int* in_sizes, int n_in,
                              void* d_out, int out_size, void* d_ws, size_t ws_size,
                              hipStream_t stream) {
  const float* input   = (const float*)d_in[0];
  const float* centres = (const float*)d_in[1];
  float* out = (float*)d_out;

  // Single fused dispatch; workspace intentionally unused.
  rbf_fused_kernel<<<(N_ROWS / 256) * (M_ROWS / 256), 512, 0, stream>>>(
      input, centres, out);
}